// Round 1
// baseline (1725.016 us; speedup 1.0000x reference)
//
#include <hip/hip_runtime.h>

typedef __attribute__((ext_vector_type(4))) float floatx4;
typedef __attribute__((ext_vector_type(8))) short short8;

// ---------- bf16 helpers (RNE) ----------
__device__ __forceinline__ float bf2f(unsigned short u) {
    union { unsigned int u; float f; } c; c.u = ((unsigned int)u) << 16; return c.f;
}
__device__ __forceinline__ unsigned short f2bf(float f) {
    union { float f; unsigned int u; } c; c.f = f;
    unsigned int r = c.u + 0x7FFFu + ((c.u >> 16) & 1u);
    return (unsigned short)(r >> 16);
}
__device__ __forceinline__ unsigned int pack2bf(float a, float b) {
    return (unsigned int)f2bf(a) | ((unsigned int)f2bf(b) << 16);
}

// ---------- async global->LDS, 16B per lane ----------
__device__ __forceinline__ void load_lds16(const unsigned short* g, unsigned short* l) {
    __builtin_amdgcn_global_load_lds(
        (__attribute__((address_space(1))) void*)(g),
        (__attribute__((address_space(3))) void*)(l), 16, 0, 0);
}

// ---------- CSR build ----------
__global__ void k_hist(const int* __restrict__ dst, const int* __restrict__ et,
                       int* __restrict__ deg, int* __restrict__ cnt4, int E) {
    int i = blockIdx.x * 256 + threadIdx.x;
    if (i < E) {
        int d = dst[i];
        atomicAdd(&deg[d], 1);
        atomicAdd(&cnt4[d * 4 + et[i]], 1);
    }
}

__global__ void k_scan(const int* __restrict__ deg, int* __restrict__ row_ptr,
                       int* __restrict__ cursor, int N) {
    __shared__ int sm[1024];
    __shared__ int carry_s;
    int tid = threadIdx.x;
    if (tid == 0) carry_s = 0;
    __syncthreads();
    int nch = (N + 1023) / 1024;
    for (int c = 0; c < nch; ++c) {
        int i = c * 1024 + tid;
        int v = (i < N) ? deg[i] : 0;
        sm[tid] = v;
        __syncthreads();
        for (int off = 1; off < 1024; off <<= 1) {
            int t = (tid >= off) ? sm[tid - off] : 0;
            __syncthreads();
            sm[tid] += t;
            __syncthreads();
        }
        int carry = carry_s;
        if (i < N) {
            int excl = carry + sm[tid] - v;
            row_ptr[i] = excl;
            cursor[i]  = excl;
        }
        __syncthreads();
        if (tid == 1023) carry_s = carry + sm[1023];
        __syncthreads();
    }
    if (tid == 0) row_ptr[N] = carry_s;
}

__global__ void k_scatter(const int* __restrict__ src, const int* __restrict__ dst,
                          const int* __restrict__ et, int* __restrict__ cursor,
                          int* __restrict__ edge_pk, int E) {
    int i = blockIdx.x * 256 + threadIdx.x;
    if (i < E) {
        int p = atomicAdd(&cursor[dst[i]], 1);
        edge_pk[p] = src[i] | (et[i] << 16);   // src < 65536 for N=50000
    }
}

// ---------- init h (bf16) into AH[:,128:256] ----------
__global__ void k_init_h(const float* __restrict__ feat, unsigned short* __restrict__ AH, int N) {
    int i = blockIdx.x * 256 + threadIdx.x;
    if (i < N * 128) {
        int v = i >> 7, d = i & 127;
        AH[(size_t)v * 256 + 128 + d] = f2bf(feat[i]);
    }
}

// ---------- weight prep: hi/lo bf16 split, n-major [Nout][K] ----------
__global__ void k_prep_wcat(const float* __restrict__ W, unsigned short* __restrict__ hi,
                            unsigned short* __restrict__ lo) {
    int i = blockIdx.x * 256 + threadIdx.x;   // 4*128*128 = 65536, flat = t*16384 + o*128 + d
    if (i < 65536) {
        int t = i >> 14, o = (i >> 7) & 127, d = i & 127;
        float w = W[i];
        unsigned short h = f2bf(w);
        int idx = o * 512 + t * 128 + d;      // [o][k], k = t*128+d
        hi[idx] = h;
        lo[idx] = f2bf(w - bf2f(h));
    }
}

__global__ void k_prep_wg(const float* __restrict__ Wih, const float* __restrict__ Whh,
                          unsigned short* __restrict__ hi, unsigned short* __restrict__ lo) {
    int i = blockIdx.x * 256 + threadIdx.x;   // 512*256
    if (i < 512 * 256) {
        int j = i >> 8, k = i & 255;          // j: out col, k over [a(128), h(128)]
        float w;
        if (j < 256)      w = (k < 128) ? Wih[j * 128 + k] : Whh[j * 128 + (k - 128)];
        else if (j < 384) w = (k < 128) ? Wih[j * 128 + k] : 0.f;   // i_n: a only
        else              w = (k < 128) ? 0.f : Whh[(j - 128) * 128 + (k - 128)]; // h_n
        unsigned short h = f2bf(w);
        hi[i] = h;
        lo[i] = f2bf(w - bf2f(h));
    }
}

// ---------- per-step: aggregate h[src] by (dst, etype): S[v][t*128+d] ----------
__global__ __launch_bounds__(256) void k_aggregate(
    const int* __restrict__ row_ptr, const int* __restrict__ edge_pk,
    const unsigned short* __restrict__ AH, unsigned short* __restrict__ S, int N)
{
    int wv = threadIdx.x >> 6;
    int lane = threadIdx.x & 63;
    int v = blockIdx.x * 4 + wv;
    if (v >= N) return;
    int beg = row_ptr[v], end = row_ptr[v + 1];
    float a0x = 0, a0y = 0, a1x = 0, a1y = 0, a2x = 0, a2y = 0, a3x = 0, a3y = 0;
    for (int e = beg; e < end; ++e) {
        int ep = edge_pk[e];                   // wave-uniform
        int s = ep & 0xFFFF;
        int t = ep >> 16;
        unsigned int hv = *(const unsigned int*)&AH[(size_t)s * 256 + 128 + lane * 2];
        float x0 = bf2f((unsigned short)(hv & 0xFFFF));
        float x1 = bf2f((unsigned short)(hv >> 16));
        if (t == 0)      { a0x += x0; a0y += x1; }
        else if (t == 1) { a1x += x0; a1y += x1; }
        else if (t == 2) { a2x += x0; a2y += x1; }
        else             { a3x += x0; a3y += x1; }
    }
    unsigned int* Sp = (unsigned int*)&S[(size_t)v * 512];
    Sp[lane]       = pack2bf(a0x, a0y);
    Sp[64 + lane]  = pack2bf(a1x, a1y);
    Sp[128 + lane] = pack2bf(a2x, a2y);
    Sp[192 + lane] = pack2bf(a3x, a3y);
}

// ---------- GEMM: C[128,128] tile, 4 waves, 16x16x32 bf16 MFMA, hi+lo weight passes ----------
// MODE 0: out = bf16 a into AH[:,0:128], + per-etype-count bias.  MODE 1: out = fp32 G[N,512].
template <int MODE>
__global__ __launch_bounds__(256) void k_gemm(
    const unsigned short* __restrict__ A, int lda, int Ktot, int M,
    const unsigned short* __restrict__ Bhi, const unsigned short* __restrict__ Blo,
    unsigned short* __restrict__ outAH, const int* __restrict__ cnt4,
    const float* __restrict__ b_et, float* __restrict__ G)
{
    __shared__ __align__(16) unsigned short As[128 * 32];
    __shared__ __align__(16) unsigned short Bhs[128 * 32];
    __shared__ __align__(16) unsigned short Bls[128 * 32];
    const int tid  = threadIdx.x;
    const int lane = tid & 63;
    const int wv   = tid >> 6;
    const int wm   = (wv & 1) * 64;
    const int wn   = (wv >> 1) * 64;
    const int mBase = blockIdx.x * 128;
    const int nBase = blockIdx.y * 128;
    const int srow = tid >> 2;         // 0..63
    const int sseg = (tid & 3) * 8;    // element offset within 32-wide row

    floatx4 acc[4][4];
#pragma unroll
    for (int i = 0; i < 4; ++i)
#pragma unroll
        for (int j = 0; j < 4; ++j) acc[i][j] = (floatx4){0.f, 0.f, 0.f, 0.f};

    for (int k0 = 0; k0 < Ktot; k0 += 32) {
        __syncthreads();
        {
            int r0 = mBase + srow;      if (r0 >= M) r0 = M - 1;
            int r1 = mBase + srow + 64; if (r1 >= M) r1 = M - 1;
            load_lds16(A + (size_t)r0 * lda + k0 + sseg, &As[srow * 32 + sseg]);
            load_lds16(A + (size_t)r1 * lda + k0 + sseg, &As[(srow + 64) * 32 + sseg]);
            const unsigned short* bh = Bhi + (size_t)(nBase + srow) * Ktot + k0 + sseg;
            load_lds16(bh,                     &Bhs[srow * 32 + sseg]);
            load_lds16(bh + (size_t)64 * Ktot, &Bhs[(srow + 64) * 32 + sseg]);
            const unsigned short* bl = Blo + (size_t)(nBase + srow) * Ktot + k0 + sseg;
            load_lds16(bl,                     &Bls[srow * 32 + sseg]);
            load_lds16(bl + (size_t)64 * Ktot, &Bls[(srow + 64) * 32 + sseg]);
        }
        __syncthreads();
        const int kof = (lane >> 4) * 8;
        const int mr  = lane & 15;
        short8 af[4], bh[4], bl[4];
#pragma unroll
        for (int i = 0; i < 4; ++i) af[i] = *(const short8*)&As[(wm + i * 16 + mr) * 32 + kof];
#pragma unroll
        for (int j = 0; j < 4; ++j) bh[j] = *(const short8*)&Bhs[(wn + j * 16 + mr) * 32 + kof];
#pragma unroll
        for (int j = 0; j < 4; ++j) bl[j] = *(const short8*)&Bls[(wn + j * 16 + mr) * 32 + kof];
#pragma unroll
        for (int i = 0; i < 4; ++i)
#pragma unroll
            for (int j = 0; j < 4; ++j) {
                acc[i][j] = __builtin_amdgcn_mfma_f32_16x16x32_bf16(af[i], bh[j], acc[i][j], 0, 0, 0);
                acc[i][j] = __builtin_amdgcn_mfma_f32_16x16x32_bf16(af[i], bl[j], acc[i][j], 0, 0, 0);
            }
    }

    const int mr4 = (lane >> 4) * 4;
    const int nc  = lane & 15;
#pragma unroll
    for (int i = 0; i < 4; ++i) {
#pragma unroll
        for (int r = 0; r < 4; ++r) {
            int row = mBase + wm + i * 16 + mr4 + r;
            if (row < M) {
                if (MODE == 0) {
                    int cx = cnt4[row * 4 + 0], cy = cnt4[row * 4 + 1];
                    int cz = cnt4[row * 4 + 2], cw = cnt4[row * 4 + 3];
#pragma unroll
                    for (int j = 0; j < 4; ++j) {
                        int col = wn + j * 16 + nc;
                        float val = acc[i][j][r]
                            + (float)cx * b_et[col]       + (float)cy * b_et[128 + col]
                            + (float)cz * b_et[256 + col] + (float)cw * b_et[384 + col];
                        outAH[(size_t)row * 256 + col] = f2bf(val);
                    }
                } else {
#pragma unroll
                    for (int j = 0; j < 4; ++j) {
                        int col = nBase + wn + j * 16 + nc;
                        G[(size_t)row * 512 + col] = acc[i][j][r];
                    }
                }
            }
        }
    }
}

// ---------- GRU elementwise ----------
__global__ void k_gru(const float* __restrict__ G, unsigned short* __restrict__ AH,
                      const float* __restrict__ b_ih, const float* __restrict__ b_hh, int N) {
    int i = blockIdx.x * 256 + threadIdx.x;
    if (i >= N * 128) return;
    int v = i >> 7, d = i & 127;
    const float* g = G + (size_t)v * 512;
    float pre_r = g[d]       + b_ih[d]       + b_hh[d];
    float pre_z = g[128 + d] + b_ih[128 + d] + b_hh[128 + d];
    float i_n   = g[256 + d] + b_ih[256 + d];
    float h_n   = g[384 + d] + b_hh[256 + d];
    float r = 1.f / (1.f + __expf(-pre_r));
    float z = 1.f / (1.f + __expf(-pre_z));
    float n = tanhf(i_n + r * h_n);
    size_t hidx = (size_t)v * 256 + 128 + d;
    float h = bf2f(AH[hidx]);
    AH[hidx] = f2bf((1.f - z) * n + z * h);
}

// ---------- readout: per-graph sum (graph_ids sorted) + classifier + sigmoid ----------
__global__ void k_readout(const unsigned short* __restrict__ AH, const int* __restrict__ gids,
                          const float* __restrict__ cls_w, const float* __restrict__ cls_b,
                          float* __restrict__ out, int N) {
    int g = blockIdx.x;
    int d = threadIdx.x;   // 128
    int lo = 0, hi = N;
    while (lo < hi) { int m = (lo + hi) >> 1; if (gids[m] < g) lo = m + 1; else hi = m; }
    int s = lo;
    lo = 0; hi = N;
    while (lo < hi) { int m = (lo + hi) >> 1; if (gids[m] < g + 1) lo = m + 1; else hi = m; }
    int e = lo;
    float acc = 0.f;
    for (int v = s; v < e; ++v) acc += bf2f(AH[(size_t)v * 256 + 128 + d]);
    __shared__ float red[128];
    red[d] = acc * cls_w[d];
    __syncthreads();
    for (int off = 64; off > 0; off >>= 1) {
        if (d < off) red[d] += red[d + off];
        __syncthreads();
    }
    if (d == 0) out[g] = 1.f / (1.f + expf(-(red[0] + cls_b[0])));
}

// ---------- host ----------
extern "C" void kernel_launch(void* const* d_in, const int* in_sizes, int n_in,
                              void* d_out, int out_size, void* d_ws, size_t ws_size,
                              hipStream_t stream) {
    const float* features = (const float*)d_in[0];
    const int*   src      = (const int*)d_in[1];
    const int*   dst      = (const int*)d_in[2];
    const int*   etype    = (const int*)d_in[3];
    const int*   gids     = (const int*)d_in[4];
    const float* W_etype  = (const float*)d_in[5];
    const float* b_etype  = (const float*)d_in[6];
    const float* W_ih     = (const float*)d_in[7];
    const float* W_hh     = (const float*)d_in[8];
    const float* b_ih     = (const float*)d_in[9];
    const float* b_hh     = (const float*)d_in[10];
    const float* cls_w    = (const float*)d_in[11];
    const float* cls_b    = (const float*)d_in[12];
    const int N = in_sizes[0] / 128;
    const int E = in_sizes[1];
    float* out = (float*)d_out;

    char* ws = (char*)d_ws;
    size_t off = 0;
    auto alloc = [&](size_t bytes) -> void* {
        off = (off + 255) & ~(size_t)255;
        void* p = ws + off;
        off += bytes;
        return p;
    };
    unsigned short* AH    = (unsigned short*)alloc((size_t)N * 256 * 2); // [a | h] bf16
    unsigned short* S     = (unsigned short*)alloc((size_t)N * 512 * 2);
    float*          G     = (float*)alloc((size_t)N * 512 * 4);
    unsigned short* Wc_hi = (unsigned short*)alloc(128 * 512 * 2);
    unsigned short* Wc_lo = (unsigned short*)alloc(128 * 512 * 2);
    unsigned short* Wg_hi = (unsigned short*)alloc(512 * 256 * 2);
    unsigned short* Wg_lo = (unsigned short*)alloc(512 * 256 * 2);
    int* deg     = (int*)alloc((size_t)N * 4);
    int* row_ptr = (int*)alloc((size_t)(N + 1) * 4);
    int* cursor  = (int*)alloc((size_t)N * 4);
    int* cnt4    = (int*)alloc((size_t)N * 16);
    int* edge_pk = (int*)alloc((size_t)E * 4);
    (void)ws_size; (void)n_in;

    hipMemsetAsync(deg, 0, (size_t)N * 4, stream);
    hipMemsetAsync(cnt4, 0, (size_t)N * 16, stream);
    k_hist<<<(E + 255) / 256, 256, 0, stream>>>(dst, etype, deg, cnt4, E);
    k_scan<<<1, 1024, 0, stream>>>(deg, row_ptr, cursor, N);
    k_scatter<<<(E + 255) / 256, 256, 0, stream>>>(src, dst, etype, cursor, edge_pk, E);
    k_init_h<<<(N * 128 + 255) / 256, 256, 0, stream>>>(features, AH, N);
    k_prep_wcat<<<65536 / 256, 256, 0, stream>>>(W_etype, Wc_hi, Wc_lo);
    k_prep_wg<<<(512 * 256) / 256, 256, 0, stream>>>(W_ih, W_hh, Wg_hi, Wg_lo);

    const int mblocks = (N + 127) / 128;
    for (int s = 0; s < 8; ++s) {
        k_aggregate<<<(N + 3) / 4, 256, 0, stream>>>(row_ptr, edge_pk, AH, S, N);
        dim3 g1(mblocks, 1);
        k_gemm<0><<<g1, 256, 0, stream>>>(S, 512, 512, N, Wc_hi, Wc_lo, AH, cnt4, b_etype, nullptr);
        dim3 g2(mblocks, 4);
        k_gemm<1><<<g2, 256, 0, stream>>>(AH, 256, 256, N, Wg_hi, Wg_lo, nullptr, nullptr, nullptr, G);
        k_gru<<<(N * 128 + 255) / 256, 256, 0, stream>>>(G, AH, b_ih, b_hh, N);
    }
    k_readout<<<out_size, 128, 0, stream>>>(AH, gids, cls_w, cls_b, out, N);
}